// Round 10
// baseline (536.759 us; speedup 1.0000x reference)
//
#include <hip/hip_runtime.h>
#include <hip/hip_bf16.h>
#include <math.h>

#define NN 50000
#define NE 800000
#define NR 16
#define DD 64
#define OSTRIDE 192   // 3*D concat output stride
#define QSTRIDE 1032  // ushorts per node row in q_lds (1024 + 8 pad, anti-conflict)

typedef __attribute__((ext_vector_type(8))) short bf16x8;
typedef __attribute__((ext_vector_type(4))) float f32x4;

__device__ inline float tanh_fast(float x) {
    return 1.f - 2.f / (__expf(2.f * x) + 1.f);
}
__device__ inline unsigned short f2bf(float f) {   // RNE f32 -> bf16
    unsigned u = __float_as_uint(f);
    return (unsigned short)((u + 0x7fffu + ((u >> 16) & 1u)) >> 16);
}
__device__ inline float bf2f(unsigned short s) {
    return __uint_as_float((unsigned)s << 16);
}

// ---------- CSR build ----------
__global__ void k_deg(const int* __restrict__ dst, int* __restrict__ cnt) {
    for (int e = blockIdx.x * blockDim.x + threadIdx.x; e < NE;
         e += gridDim.x * blockDim.x)
        atomicAdd(&cnt[dst[e]], 1);
}

// hierarchical exclusive scan over cnt[NN] -> rowptr, cursor
__global__ __launch_bounds__(256) void k_scan1(const int* __restrict__ cnt,
                                               int* __restrict__ rowptr,
                                               int* __restrict__ bsum) {
    __shared__ int sh[256];
    int b = blockIdx.x, t = threadIdx.x;
    int i = b * 256 + t;
    int v = (i < NN) ? cnt[i] : 0;
    sh[t] = v;
    __syncthreads();
    #pragma unroll
    for (int o = 1; o < 256; o <<= 1) {
        int u = (t >= o) ? sh[t - o] : 0;
        __syncthreads();
        sh[t] += u;
        __syncthreads();
    }
    if (i < NN) rowptr[i] = sh[t] - v;     // local exclusive
    if (t == 255) bsum[b] = sh[255];
}

__global__ __launch_bounds__(256) void k_scan2(int* __restrict__ bsum, int nb) {
    __shared__ int sh[256];
    int t = threadIdx.x;
    int v = (t < nb) ? bsum[t] : 0;
    sh[t] = v;
    __syncthreads();
    #pragma unroll
    for (int o = 1; o < 256; o <<= 1) {
        int u = (t >= o) ? sh[t - o] : 0;
        __syncthreads();
        sh[t] += u;
        __syncthreads();
    }
    if (t < nb) bsum[t] = sh[t] - v;       // exclusive block offsets
}

__global__ __launch_bounds__(256) void k_scan3(int* __restrict__ rowptr,
                                               const int* __restrict__ bsum,
                                               int* __restrict__ cursor) {
    int b = blockIdx.x, t = threadIdx.x;
    int i = b * 256 + t;
    if (i < NN) {
        int v = rowptr[i] + bsum[b];
        rowptr[i] = v;
        cursor[i] = v;
    }
    if (i == 0) rowptr[NN] = NE;
}

// epack[pos] = src | (rel<<16)
__global__ void k_fill(const int* __restrict__ dst, const int* __restrict__ src,
                       const int* __restrict__ rel, int* __restrict__ cursor,
                       int* __restrict__ epack) {
    for (int e = blockIdx.x * blockDim.x + threadIdx.x; e < NE;
         e += gridDim.x * blockDim.x) {
        int pos = atomicAdd(&cursor[dst[e]], 1);
        epack[pos] = src[e] | (rel[e] << 16);
    }
}

// ---------- h0 gather (f32 out slice + bf16 shadow) ----------
__global__ void k_copy_h0(const int* __restrict__ node_ids,
                          const float* __restrict__ ent,
                          float* __restrict__ out,
                          unsigned short* __restrict__ hbf) {
    int i = blockIdx.x * blockDim.x + threadIdx.x;
    if (i >= NN * DD) return;
    int n = i >> 6, d = i & 63;
    float v = ent[(size_t)node_ids[n] * DD + d];
    out[(size_t)n * OSTRIDE + d] = v;
    hbf[(size_t)n * DD + d] = f2bf(v);
}

// ---------- W -> bf16 tables: wbf[r][d][E], wtbf[r][E][d] ----------
__global__ void k_wprep(const float* __restrict__ W, unsigned short* __restrict__ wbf,
                        unsigned short* __restrict__ wtbf) {
    int i = blockIdx.x * blockDim.x + threadIdx.x;   // 16*64*64 = 65536
    if (i >= NR * DD * DD) return;
    int r = i >> 12, rem = i & 4095, d = rem >> 6, E = rem & 63;
    unsigned short v = f2bf(W[i]);
    wbf[i] = v;
    wtbf[(r << 12) | (E << 6) | d] = v;
}

// ---------- FUSED: per-block q compute (MFMA, LDS-only) + edge softmax/aggregate ----
// Block = 16 dst nodes, 4 waves. Phase 1: wave w computes q[*, r] for
// r in {w, w+4, w+8, w+12} into q_lds (never hits HBM). One barrier.
// Phase 2: wave w runs edge loops for its 4 nodes, q read from LDS.
__global__ __launch_bounds__(256) void k_fused5(const unsigned short* __restrict__ hbf,
                                                const unsigned short* __restrict__ wbf,
                                                const unsigned short* __restrict__ wtbf,
                                                const float* __restrict__ relE,
                                                const int* __restrict__ rowptr,
                                                const int* __restrict__ epack,
                                                float* __restrict__ h_nb) {
    __shared__ __align__(16) unsigned short q_lds[16 * QSTRIDE];  // [ni][r*64+d], 33KB
    __shared__ __align__(16) unsigned short u_lds[4][16][72];     // wave-private, 9KB
    int n0 = blockIdx.x * 16;
    int t  = threadIdx.x;
    int w  = t >> 6, l = t & 63;
    int l15 = l & 15, lg = l >> 4;

    // ---- Phase 1: q[n, r, :] = W_r @ tanh(h[n,:]@W_r + e_r) for the 16-node tile ----
    int ar = n0 + l15; if (ar >= NN) ar = NN - 1;
    const unsigned short* ap = hbf + (size_t)ar * DD + lg * 8;
    bf16x8 a0 = *(const bf16x8*)ap;
    bf16x8 a1 = *(const bf16x8*)(ap + 32);

    for (int rr = 0; rr < 4; ++rr) {
        int r = w + rr * 4;

        // GEMM1: T[m,E] = h[m,:] @ W_r  (B = wtbf rows = B^T)
        f32x4 acc[4];
        #pragma unroll
        for (int nt = 0; nt < 4; ++nt) acc[nt] = (f32x4){0.f, 0.f, 0.f, 0.f};
        const unsigned short* wtr = wtbf + (r << 12);
        #pragma unroll
        for (int nt = 0; nt < 4; ++nt) {
            const unsigned short* bp = wtr + (nt * 16 + l15) * DD + lg * 8;
            bf16x8 b0 = *(const bf16x8*)bp;
            bf16x8 b1 = *(const bf16x8*)(bp + 32);
            acc[nt] = __builtin_amdgcn_mfma_f32_16x16x32_bf16(a0, b0, acc[nt], 0, 0, 0);
            acc[nt] = __builtin_amdgcn_mfma_f32_16x16x32_bf16(a1, b1, acc[nt], 0, 0, 0);
        }

        // U = tanh(T + e_r) -> wave-private u_lds (per-wave DS ops are in-order)
        #pragma unroll
        for (int nt = 0; nt < 4; ++nt) {
            int E = nt * 16 + l15;
            float er = relE[r * DD + E];
            #pragma unroll
            for (int reg = 0; reg < 4; ++reg)
                u_lds[w][lg * 4 + reg][E] = f2bf(tanh_fast(acc[nt][reg] + er));
        }
        asm volatile("s_waitcnt lgkmcnt(0)" ::: "memory");

        // GEMM2: Q[m,d] = U[m,:] @ W_r^T  (B = wbf rows = B^T)
        const unsigned short* up = &u_lds[w][l15][lg * 8];
        bf16x8 u0 = *(const bf16x8*)up;
        bf16x8 u1 = *(const bf16x8*)(up + 32);

        f32x4 q4[4];
        #pragma unroll
        for (int nt = 0; nt < 4; ++nt) q4[nt] = (f32x4){0.f, 0.f, 0.f, 0.f};
        const unsigned short* wr = wbf + (r << 12);
        #pragma unroll
        for (int nt = 0; nt < 4; ++nt) {
            const unsigned short* bp = wr + (nt * 16 + l15) * DD + lg * 8;
            bf16x8 b0 = *(const bf16x8*)bp;
            bf16x8 b1 = *(const bf16x8*)(bp + 32);
            q4[nt] = __builtin_amdgcn_mfma_f32_16x16x32_bf16(u0, b0, q4[nt], 0, 0, 0);
            q4[nt] = __builtin_amdgcn_mfma_f32_16x16x32_bf16(u1, b1, q4[nt], 0, 0, 0);
        }

        // store to q_lds[m][r*64 + d]
        #pragma unroll
        for (int reg = 0; reg < 4; ++reg) {
            unsigned short* qp = q_lds + (lg * 4 + reg) * QSTRIDE + r * 64 + l15;
            #pragma unroll
            for (int nt = 0; nt < 4; ++nt)
                qp[nt * 16] = f2bf(q4[nt][reg]);
        }
    }
    __syncthreads();

    // ---- Phase 2: edge loops, wave w handles nodes n0 + 4w .. 4w+3 ----
    int lane = l;
    bool s0 = lane & 1, s1 = lane & 2, s2 = lane & 4;
    for (int kk = 0; kk < 4; ++kk) {
        int ni = (w << 2) + kk;
        int n = n0 + ni;
        if (n >= NN) continue;
        const unsigned short* ql = q_lds + ni * QSTRIDE;
        int row0 = rowptr[n], deg = rowptr[n + 1] - row0;

        float m = -__builtin_inff(), zr = 0.f, acc = 0.f;
        int i = 0;
        for (; i + 8 <= deg; i += 8) {
            float v[8], hv[8];
            #pragma unroll
            for (int j = 0; j < 8; ++j) {
                int p = epack[row0 + i + j];
                int s = p & 0xffff, r = p >> 16;
                hv[j] = bf2f(hbf[(size_t)s * DD + lane]);
                v[j]  = hv[j] * bf2f(ql[r * DD + lane]);
            }
            float x0 = s0 ? v[1] : v[0], o0 = s0 ? v[0] : v[1];
            float x1 = s0 ? v[3] : v[2], o1 = s0 ? v[2] : v[3];
            float x2 = s0 ? v[5] : v[4], o2 = s0 ? v[4] : v[5];
            float x3 = s0 ? v[7] : v[6], o3 = s0 ? v[6] : v[7];
            x0 += __shfl_xor(o0, 1, 64);
            x1 += __shfl_xor(o1, 1, 64);
            x2 += __shfl_xor(o2, 1, 64);
            x3 += __shfl_xor(o3, 1, 64);
            float y0 = s1 ? x1 : x0, p0 = s1 ? x0 : x1;
            float y1 = s1 ? x3 : x2, p1 = s1 ? x2 : x3;
            y0 += __shfl_xor(p0, 2, 64);
            y1 += __shfl_xor(p1, 2, 64);
            float sj = s2 ? y1 : y0, q0 = s2 ? y0 : y1;
            sj += __shfl_xor(q0, 4, 64);
            sj += __shfl_xor(sj, 8, 64);
            sj += __shfl_xor(sj, 16, 64);
            sj += __shfl_xor(sj, 32, 64);

            float cm = sj;
            cm = fmaxf(cm, __shfl_xor(cm, 1, 64));
            cm = fmaxf(cm, __shfl_xor(cm, 2, 64));
            cm = fmaxf(cm, __shfl_xor(cm, 4, 64));
            float mn = fmaxf(m, cm);
            float sc = __expf(m - mn);
            float wgt = __expf(sj - mn);
            float zn = wgt;
            zn += __shfl_xor(zn, 1, 64);
            zn += __shfl_xor(zn, 2, 64);
            zn += __shfl_xor(zn, 4, 64);
            zr = zr * sc + zn;
            acc *= sc;
            #pragma unroll
            for (int j = 0; j < 8; ++j)
                acc += __shfl(wgt, j, 8) * hv[j];
            m = mn;
        }
        for (; i < deg; ++i) {
            int p = epack[row0 + i];
            int s = p & 0xffff, r = p >> 16;
            float hsv = bf2f(hbf[(size_t)s * DD + lane]);
            float v = hsv * bf2f(ql[r * DD + lane]);
            #pragma unroll
            for (int o = 32; o; o >>= 1) v += __shfl_xor(v, o, 64);
            float mn = fmaxf(m, v);
            float sc = __expf(m - mn);
            float wgt = __expf(v - mn);
            zr  = zr * sc + wgt;
            acc = acc * sc + wgt * hsv;
            m = mn;
        }
        h_nb[(size_t)n * DD + lane] = (deg > 0) ? acc / zr : 0.f;
    }
}

// ---------- epilogue GEMM (f32) + bf16 shadow of new h ----------
__global__ __launch_bounds__(256) void k_out2(const float* __restrict__ h_nb,
                                              const float* __restrict__ ra,
                                              const float* __restrict__ rb,
                                              float* __restrict__ out,
                                              int off_in, int off_out,
                                              unsigned short* __restrict__ hbf) {
    __shared__ __align__(16) float v1s[64][68];
    __shared__ __align__(16) float v2s[64][68];
    __shared__ __align__(16) float ws[2][64][64];
    int t = threadIdx.x;
    int n0 = blockIdx.x * 64;

    for (int i = t; i < 1024; i += 256) {
        int ni = i >> 4, c4 = (i & 15) * 4;
        int n = n0 + ni;
        float4 hv = make_float4(0.f, 0.f, 0.f, 0.f);
        float4 nb = make_float4(0.f, 0.f, 0.f, 0.f);
        if (n < NN) {
            hv = *(const float4*)&out[(size_t)n * OSTRIDE + off_in + c4];
            nb = *(const float4*)&h_nb[(size_t)n * DD + c4];
        }
        v1s[c4 + 0][ni] = hv.x + nb.x;  v2s[c4 + 0][ni] = hv.x * nb.x;
        v1s[c4 + 1][ni] = hv.y + nb.y;  v2s[c4 + 1][ni] = hv.y * nb.y;
        v1s[c4 + 2][ni] = hv.z + nb.z;  v2s[c4 + 2][ni] = hv.z * nb.z;
        v1s[c4 + 3][ni] = hv.w + nb.w;  v2s[c4 + 3][ni] = hv.w * nb.w;
    }
    for (int i = t; i < 2048; i += 256) {
        const float* base = (i < 1024) ? ra : rb;
        int rem = i & 1023;
        float4 v = *(const float4*)&base[rem * 4];
        int k = rem >> 4, c4 = (rem & 15) * 4;
        *(float4*)&ws[i >> 10][k][c4] = v;
    }
    __syncthreads();

    int nd0 = (t >> 4) * 4;
    int c0  = (t & 15) * 4;
    float a1[4][4] = {}, a2[4][4] = {};
    #pragma unroll 8
    for (int k = 0; k < 64; ++k) {
        float4 h1 = *(const float4*)&v1s[k][nd0];
        float4 h2 = *(const float4*)&v2s[k][nd0];
        float4 wa = *(const float4*)&ws[0][k][c0];
        float4 wb = *(const float4*)&ws[1][k][c0];
        float x1[4] = {h1.x, h1.y, h1.z, h1.w};
        float x2[4] = {h2.x, h2.y, h2.z, h2.w};
        #pragma unroll
        for (int i = 0; i < 4; ++i) {
            a1[i][0] += x1[i] * wa.x; a1[i][1] += x1[i] * wa.y;
            a1[i][2] += x1[i] * wa.z; a1[i][3] += x1[i] * wa.w;
            a2[i][0] += x2[i] * wb.x; a2[i][1] += x2[i] * wb.y;
            a2[i][2] += x2[i] * wb.z; a2[i][3] += x2[i] * wb.w;
        }
    }
    #pragma unroll
    for (int i = 0; i < 4; ++i) {
        int n = n0 + nd0 + i;
        if (n >= NN) continue;
        float4 o;
        float* po = (float*)&o;
        #pragma unroll
        for (int j = 0; j < 4; ++j) {
            float u1 = a1[i][j], u2 = a2[i][j];
            u1 = u1 > 0.f ? u1 : 0.01f * u1;
            u2 = u2 > 0.f ? u2 : 0.01f * u2;
            po[j] = u1 + u2;
        }
        *(float4*)&out[(size_t)n * OSTRIDE + off_out + c0] = o;
        hbf[(size_t)n * DD + c0 + 0] = f2bf(o.x);
        hbf[(size_t)n * DD + c0 + 1] = f2bf(o.y);
        hbf[(size_t)n * DD + c0 + 2] = f2bf(o.z);
        hbf[(size_t)n * DD + c0 + 3] = f2bf(o.w);
    }
}

// ---------- launch ----------
extern "C" void kernel_launch(void* const* d_in, const int* in_sizes, int n_in,
                              void* d_out, int out_size, void* d_ws, size_t ws_size,
                              hipStream_t stream) {
    const int*   node_ids = (const int*)d_in[0];
    const int*   rel_ids  = (const int*)d_in[1];
    const int*   src      = (const int*)d_in[2];
    const int*   dst      = (const int*)d_in[3];
    const float* ent      = (const float*)d_in[4];
    const float* relE     = (const float*)d_in[5];
    const float* W[2]  = {(const float*)d_in[6], (const float*)d_in[7]};
    const float* ra[2] = {(const float*)d_in[8], (const float*)d_in[10]};
    const float* rb[2] = {(const float*)d_in[9], (const float*)d_in[11]};
    float* out = (float*)d_out;

    const size_t hnb_bytes    = (size_t)NN * DD * sizeof(float);            // 12.8 MB
    const size_t hbf_bytes    = (size_t)NN * DD * sizeof(short);            // 6.4 MB
    const size_t wbf_bytes    = (size_t)NR * DD * DD * sizeof(short);       // 128 KB
    const size_t epack_bytes  = (size_t)NE * sizeof(int);                   // 3.2 MB
    const size_t rowptr_bytes = (size_t)(NN + 1) * sizeof(int);
    const size_t cnt_bytes    = (size_t)NN * sizeof(int);
    const int    NB_SCAN      = (NN + 255) / 256;   // 196
    const size_t bsum_bytes   = (size_t)256 * sizeof(int);

    char* p = (char*)d_ws;
    float*          h_nb   = (float*)p;          p += hnb_bytes;
    unsigned short* hbf    = (unsigned short*)p; p += hbf_bytes;
    unsigned short* wbf    = (unsigned short*)p; p += wbf_bytes;
    unsigned short* wtbf   = (unsigned short*)p; p += wbf_bytes;
    int*            epack  = (int*)p;            p += epack_bytes;
    int*            rowptr = (int*)p;            p += rowptr_bytes;
    int*            cnt    = (int*)p;            p += cnt_bytes;
    int*            bsum   = (int*)p;            p += bsum_bytes;
    (void)ws_size;

    // ---- CSR build (shared by both layers) ----
    hipMemsetAsync(cnt, 0, cnt_bytes, stream);
    k_deg  <<<1024, 256, 0, stream>>>(dst, cnt);
    k_scan1<<<NB_SCAN, 256, 0, stream>>>(cnt, rowptr, bsum);
    k_scan2<<<1, 256, 0, stream>>>(bsum, NB_SCAN);
    k_scan3<<<NB_SCAN, 256, 0, stream>>>(rowptr, bsum, cnt);
    k_fill <<<1024, 256, 0, stream>>>(dst, src, rel_ids, cnt, epack);

    // ---- h0 ----
    k_copy_h0<<<(NN * DD + 255) / 256, 256, 0, stream>>>(node_ids, ent, out, hbf);

    for (int L = 0; L < 2; ++L) {
        int off_in = L * DD;
        int off_out = (L + 1) * DD;

        k_wprep <<<(NR * DD * DD + 255) / 256, 256, 0, stream>>>(W[L], wbf, wtbf);
        k_fused5<<<(NN + 15) / 16, 256, 0, stream>>>(hbf, wbf, wtbf, relE,
                                                     rowptr, epack, h_nb);
        k_out2  <<<(NN + 63) / 64, 256, 0, stream>>>(h_nb, ra[L], rb[L], out,
                                                     off_in, off_out, hbf);
    }
}

// Round 11
// 458.735 us; speedup vs baseline: 1.1701x; 1.1701x over previous
//
#include <hip/hip_runtime.h>
#include <hip/hip_bf16.h>
#include <math.h>

#define NN 50000
#define NE 800000
#define NR 16
#define DD 64
#define OSTRIDE 192   // 3*D concat output stride
#define QSTRIDE 1032  // ushorts per node row in q_lds (1024 + 8 pad, anti-conflict)

typedef __attribute__((ext_vector_type(8))) short bf16x8;
typedef __attribute__((ext_vector_type(4))) float f32x4;

__device__ inline float tanh_fast(float x) {
    return 1.f - 2.f / (__expf(2.f * x) + 1.f);
}
__device__ inline unsigned short f2bf(float f) {   // RNE f32 -> bf16
    unsigned u = __float_as_uint(f);
    return (unsigned short)((u + 0x7fffu + ((u >> 16) & 1u)) >> 16);
}
__device__ inline float bf2f(unsigned short s) {
    return __uint_as_float((unsigned)s << 16);
}

// ---------- CSR build ----------
__global__ void k_deg(const int* __restrict__ dst, int* __restrict__ cnt) {
    for (int e = blockIdx.x * blockDim.x + threadIdx.x; e < NE;
         e += gridDim.x * blockDim.x)
        atomicAdd(&cnt[dst[e]], 1);
}

// hierarchical exclusive scan over cnt[NN] -> rowptr, cursor
__global__ __launch_bounds__(256) void k_scan1(const int* __restrict__ cnt,
                                               int* __restrict__ rowptr,
                                               int* __restrict__ bsum) {
    __shared__ int sh[256];
    int b = blockIdx.x, t = threadIdx.x;
    int i = b * 256 + t;
    int v = (i < NN) ? cnt[i] : 0;
    sh[t] = v;
    __syncthreads();
    #pragma unroll
    for (int o = 1; o < 256; o <<= 1) {
        int u = (t >= o) ? sh[t - o] : 0;
        __syncthreads();
        sh[t] += u;
        __syncthreads();
    }
    if (i < NN) rowptr[i] = sh[t] - v;     // local exclusive
    if (t == 255) bsum[b] = sh[255];
}

__global__ __launch_bounds__(256) void k_scan2(int* __restrict__ bsum, int nb) {
    __shared__ int sh[256];
    int t = threadIdx.x;
    int v = (t < nb) ? bsum[t] : 0;
    sh[t] = v;
    __syncthreads();
    #pragma unroll
    for (int o = 1; o < 256; o <<= 1) {
        int u = (t >= o) ? sh[t - o] : 0;
        __syncthreads();
        sh[t] += u;
        __syncthreads();
    }
    if (t < nb) bsum[t] = sh[t] - v;       // exclusive block offsets
}

__global__ __launch_bounds__(256) void k_scan3(int* __restrict__ rowptr,
                                               const int* __restrict__ bsum,
                                               int* __restrict__ cursor) {
    int b = blockIdx.x, t = threadIdx.x;
    int i = b * 256 + t;
    if (i < NN) {
        int v = rowptr[i] + bsum[b];
        rowptr[i] = v;
        cursor[i] = v;
    }
    if (i == 0) rowptr[NN] = NE;
}

// epack[pos] = src | (rel<<16)
__global__ void k_fill(const int* __restrict__ dst, const int* __restrict__ src,
                       const int* __restrict__ rel, int* __restrict__ cursor,
                       int* __restrict__ epack) {
    for (int e = blockIdx.x * blockDim.x + threadIdx.x; e < NE;
         e += gridDim.x * blockDim.x) {
        int pos = atomicAdd(&cursor[dst[e]], 1);
        epack[pos] = src[e] | (rel[e] << 16);
    }
}

// ---------- h0 gather (f32 out slice + bf16 shadow) ----------
__global__ void k_copy_h0(const int* __restrict__ node_ids,
                          const float* __restrict__ ent,
                          float* __restrict__ out,
                          unsigned short* __restrict__ hbf) {
    int i = blockIdx.x * blockDim.x + threadIdx.x;
    if (i >= NN * DD) return;
    int n = i >> 6, d = i & 63;
    float v = ent[(size_t)node_ids[n] * DD + d];
    out[(size_t)n * OSTRIDE + d] = v;
    hbf[(size_t)n * DD + d] = f2bf(v);
}

// ---------- W -> bf16 tables: wbf[r][d][E], wtbf[r][E][d] ----------
__global__ void k_wprep(const float* __restrict__ W, unsigned short* __restrict__ wbf,
                        unsigned short* __restrict__ wtbf) {
    int i = blockIdx.x * blockDim.x + threadIdx.x;   // 16*64*64 = 65536
    if (i >= NR * DD * DD) return;
    int r = i >> 12, rem = i & 4095, d = rem >> 6, E = rem & 63;
    unsigned short v = f2bf(W[i]);
    wbf[i] = v;
    wtbf[(r << 12) | (E << 6) | d] = v;
}

// ---------- FUSED: q compute in LDS (MFMA) + edge softmax/aggregate ----------
// Block = 16 dst nodes, 1024 threads = 16 waves.
// Phase 1: wave w computes q[*, r=w] for the 16-node tile into q_lds (no HBM).
// Phase 2: wave w runs the edge loop for node n0+w (full 50K-wave parallelism).
__global__ __launch_bounds__(1024) void k_fused6(const unsigned short* __restrict__ hbf,
                                                 const unsigned short* __restrict__ wbf,
                                                 const unsigned short* __restrict__ wtbf,
                                                 const float* __restrict__ relE,
                                                 const int* __restrict__ rowptr,
                                                 const int* __restrict__ epack,
                                                 float* __restrict__ h_nb) {
    __shared__ __align__(16) unsigned short q_lds[16 * QSTRIDE];  // [ni][r*64+d], 33KB
    __shared__ __align__(16) unsigned short u_lds[16][16][72];    // per-wave slice, 37KB
    int n0 = blockIdx.x * 16;
    int t  = threadIdx.x;
    int w  = t >> 6, l = t & 63;          // wave = relation (phase1) = node (phase2)
    int l15 = l & 15, lg = l >> 4;
    int r = w;

    // ---- Phase 1: q[m, r, :] = W_r @ tanh(h[m,:]@W_r + e_r), m = 16-node tile ----
    {
        int ar = n0 + l15; if (ar >= NN) ar = NN - 1;
        const unsigned short* ap = hbf + (size_t)ar * DD + lg * 8;
        bf16x8 a0 = *(const bf16x8*)ap;
        bf16x8 a1 = *(const bf16x8*)(ap + 32);

        // GEMM1: T[m,E] = h[m,:] @ W_r  (B = wtbf rows = B^T)
        f32x4 acc[4];
        #pragma unroll
        for (int nt = 0; nt < 4; ++nt) acc[nt] = (f32x4){0.f, 0.f, 0.f, 0.f};
        const unsigned short* wtr = wtbf + (r << 12);
        #pragma unroll
        for (int nt = 0; nt < 4; ++nt) {
            const unsigned short* bp = wtr + (nt * 16 + l15) * DD + lg * 8;
            bf16x8 b0 = *(const bf16x8*)bp;
            bf16x8 b1 = *(const bf16x8*)(bp + 32);
            acc[nt] = __builtin_amdgcn_mfma_f32_16x16x32_bf16(a0, b0, acc[nt], 0, 0, 0);
            acc[nt] = __builtin_amdgcn_mfma_f32_16x16x32_bf16(a1, b1, acc[nt], 0, 0, 0);
        }

        // U = tanh(T + e_r) -> wave-private u_lds (per-wave DS ops are in-order)
        #pragma unroll
        for (int nt = 0; nt < 4; ++nt) {
            int E = nt * 16 + l15;
            float er = relE[r * DD + E];
            #pragma unroll
            for (int reg = 0; reg < 4; ++reg)
                u_lds[w][lg * 4 + reg][E] = f2bf(tanh_fast(acc[nt][reg] + er));
        }
        asm volatile("s_waitcnt lgkmcnt(0)" ::: "memory");

        // GEMM2: Q[m,d] = U[m,:] @ W_r^T  (B = wbf rows = B^T)
        const unsigned short* up = &u_lds[w][l15][lg * 8];
        bf16x8 u0 = *(const bf16x8*)up;
        bf16x8 u1 = *(const bf16x8*)(up + 32);

        f32x4 q4[4];
        #pragma unroll
        for (int nt = 0; nt < 4; ++nt) q4[nt] = (f32x4){0.f, 0.f, 0.f, 0.f};
        const unsigned short* wr = wbf + (r << 12);
        #pragma unroll
        for (int nt = 0; nt < 4; ++nt) {
            const unsigned short* bp = wr + (nt * 16 + l15) * DD + lg * 8;
            bf16x8 b0 = *(const bf16x8*)bp;
            bf16x8 b1 = *(const bf16x8*)(bp + 32);
            q4[nt] = __builtin_amdgcn_mfma_f32_16x16x32_bf16(u0, b0, q4[nt], 0, 0, 0);
            q4[nt] = __builtin_amdgcn_mfma_f32_16x16x32_bf16(u1, b1, q4[nt], 0, 0, 0);
        }

        // store to q_lds[m][r*64 + d]
        #pragma unroll
        for (int reg = 0; reg < 4; ++reg) {
            unsigned short* qp = q_lds + (lg * 4 + reg) * QSTRIDE + r * 64 + l15;
            #pragma unroll
            for (int nt = 0; nt < 4; ++nt)
                qp[nt * 16] = f2bf(q4[nt][reg]);
        }
    }
    __syncthreads();

    // ---- Phase 2: edge loop, wave w handles node n0 + w ----
    int n = n0 + w;
    if (n >= NN) return;
    int lane = l;
    const unsigned short* ql = q_lds + w * QSTRIDE;
    int row0 = rowptr[n], deg = rowptr[n + 1] - row0;

    float m = -__builtin_inff(), zr = 0.f, acc = 0.f;
    bool s0 = lane & 1, s1 = lane & 2, s2 = lane & 4;

    int i = 0;
    for (; i + 8 <= deg; i += 8) {
        float v[8], hv[8];
        #pragma unroll
        for (int j = 0; j < 8; ++j) {
            int p = epack[row0 + i + j];
            int s = p & 0xffff, rr = p >> 16;
            hv[j] = bf2f(hbf[(size_t)s * DD + lane]);
            v[j]  = hv[j] * bf2f(ql[rr * DD + lane]);
        }
        float x0 = s0 ? v[1] : v[0], o0 = s0 ? v[0] : v[1];
        float x1 = s0 ? v[3] : v[2], o1 = s0 ? v[2] : v[3];
        float x2 = s0 ? v[5] : v[4], o2 = s0 ? v[4] : v[5];
        float x3 = s0 ? v[7] : v[6], o3 = s0 ? v[6] : v[7];
        x0 += __shfl_xor(o0, 1, 64);
        x1 += __shfl_xor(o1, 1, 64);
        x2 += __shfl_xor(o2, 1, 64);
        x3 += __shfl_xor(o3, 1, 64);
        float y0 = s1 ? x1 : x0, p0 = s1 ? x0 : x1;
        float y1 = s1 ? x3 : x2, p1 = s1 ? x2 : x3;
        y0 += __shfl_xor(p0, 2, 64);
        y1 += __shfl_xor(p1, 2, 64);
        float sj = s2 ? y1 : y0, q0 = s2 ? y0 : y1;
        sj += __shfl_xor(q0, 4, 64);
        sj += __shfl_xor(sj, 8, 64);
        sj += __shfl_xor(sj, 16, 64);
        sj += __shfl_xor(sj, 32, 64);

        float cm = sj;
        cm = fmaxf(cm, __shfl_xor(cm, 1, 64));
        cm = fmaxf(cm, __shfl_xor(cm, 2, 64));
        cm = fmaxf(cm, __shfl_xor(cm, 4, 64));
        float mn = fmaxf(m, cm);
        float sc = __expf(m - mn);
        float wgt = __expf(sj - mn);
        float zn = wgt;
        zn += __shfl_xor(zn, 1, 64);
        zn += __shfl_xor(zn, 2, 64);
        zn += __shfl_xor(zn, 4, 64);
        zr = zr * sc + zn;
        acc *= sc;
        #pragma unroll
        for (int j = 0; j < 8; ++j)
            acc += __shfl(wgt, j, 8) * hv[j];
        m = mn;
    }
    for (; i < deg; ++i) {
        int p = epack[row0 + i];
        int s = p & 0xffff, rr = p >> 16;
        float hsv = bf2f(hbf[(size_t)s * DD + lane]);
        float v = hsv * bf2f(ql[rr * DD + lane]);
        #pragma unroll
        for (int o = 32; o; o >>= 1) v += __shfl_xor(v, o, 64);
        float mn = fmaxf(m, v);
        float sc = __expf(m - mn);
        float wgt = __expf(v - mn);
        zr  = zr * sc + wgt;
        acc = acc * sc + wgt * hsv;
        m = mn;
    }
    h_nb[(size_t)n * DD + lane] = (deg > 0) ? acc / zr : 0.f;
}

// ---------- epilogue GEMM (f32) + bf16 shadow of new h ----------
__global__ __launch_bounds__(256) void k_out2(const float* __restrict__ h_nb,
                                              const float* __restrict__ ra,
                                              const float* __restrict__ rb,
                                              float* __restrict__ out,
                                              int off_in, int off_out,
                                              unsigned short* __restrict__ hbf) {
    __shared__ __align__(16) float v1s[64][68];
    __shared__ __align__(16) float v2s[64][68];
    __shared__ __align__(16) float ws[2][64][64];
    int t = threadIdx.x;
    int n0 = blockIdx.x * 64;

    for (int i = t; i < 1024; i += 256) {
        int ni = i >> 4, c4 = (i & 15) * 4;
        int n = n0 + ni;
        float4 hv = make_float4(0.f, 0.f, 0.f, 0.f);
        float4 nb = make_float4(0.f, 0.f, 0.f, 0.f);
        if (n < NN) {
            hv = *(const float4*)&out[(size_t)n * OSTRIDE + off_in + c4];
            nb = *(const float4*)&h_nb[(size_t)n * DD + c4];
        }
        v1s[c4 + 0][ni] = hv.x + nb.x;  v2s[c4 + 0][ni] = hv.x * nb.x;
        v1s[c4 + 1][ni] = hv.y + nb.y;  v2s[c4 + 1][ni] = hv.y * nb.y;
        v1s[c4 + 2][ni] = hv.z + nb.z;  v2s[c4 + 2][ni] = hv.z * nb.z;
        v1s[c4 + 3][ni] = hv.w + nb.w;  v2s[c4 + 3][ni] = hv.w * nb.w;
    }
    for (int i = t; i < 2048; i += 256) {
        const float* base = (i < 1024) ? ra : rb;
        int rem = i & 1023;
        float4 v = *(const float4*)&base[rem * 4];
        int k = rem >> 4, c4 = (rem & 15) * 4;
        *(float4*)&ws[i >> 10][k][c4] = v;
    }
    __syncthreads();

    int nd0 = (t >> 4) * 4;
    int c0  = (t & 15) * 4;
    float a1[4][4] = {}, a2[4][4] = {};
    #pragma unroll 8
    for (int k = 0; k < 64; ++k) {
        float4 h1 = *(const float4*)&v1s[k][nd0];
        float4 h2 = *(const float4*)&v2s[k][nd0];
        float4 wa = *(const float4*)&ws[0][k][c0];
        float4 wb = *(const float4*)&ws[1][k][c0];
        float x1[4] = {h1.x, h1.y, h1.z, h1.w};
        float x2[4] = {h2.x, h2.y, h2.z, h2.w};
        #pragma unroll
        for (int i = 0; i < 4; ++i) {
            a1[i][0] += x1[i] * wa.x; a1[i][1] += x1[i] * wa.y;
            a1[i][2] += x1[i] * wa.z; a1[i][3] += x1[i] * wa.w;
            a2[i][0] += x2[i] * wb.x; a2[i][1] += x2[i] * wb.y;
            a2[i][2] += x2[i] * wb.z; a2[i][3] += x2[i] * wb.w;
        }
    }
    #pragma unroll
    for (int i = 0; i < 4; ++i) {
        int n = n0 + nd0 + i;
        if (n >= NN) continue;
        float4 o;
        float* po = (float*)&o;
        #pragma unroll
        for (int j = 0; j < 4; ++j) {
            float u1 = a1[i][j], u2 = a2[i][j];
            u1 = u1 > 0.f ? u1 : 0.01f * u1;
            u2 = u2 > 0.f ? u2 : 0.01f * u2;
            po[j] = u1 + u2;
        }
        *(float4*)&out[(size_t)n * OSTRIDE + off_out + c0] = o;
        hbf[(size_t)n * DD + c0 + 0] = f2bf(o.x);
        hbf[(size_t)n * DD + c0 + 1] = f2bf(o.y);
        hbf[(size_t)n * DD + c0 + 2] = f2bf(o.z);
        hbf[(size_t)n * DD + c0 + 3] = f2bf(o.w);
    }
}

// ---------- launch ----------
extern "C" void kernel_launch(void* const* d_in, const int* in_sizes, int n_in,
                              void* d_out, int out_size, void* d_ws, size_t ws_size,
                              hipStream_t stream) {
    const int*   node_ids = (const int*)d_in[0];
    const int*   rel_ids  = (const int*)d_in[1];
    const int*   src      = (const int*)d_in[2];
    const int*   dst      = (const int*)d_in[3];
    const float* ent      = (const float*)d_in[4];
    const float* relE     = (const float*)d_in[5];
    const float* W[2]  = {(const float*)d_in[6], (const float*)d_in[7]};
    const float* ra[2] = {(const float*)d_in[8], (const float*)d_in[10]};
    const float* rb[2] = {(const float*)d_in[9], (const float*)d_in[11]};
    float* out = (float*)d_out;

    const size_t hnb_bytes    = (size_t)NN * DD * sizeof(float);            // 12.8 MB
    const size_t hbf_bytes    = (size_t)NN * DD * sizeof(short);            // 6.4 MB
    const size_t wbf_bytes    = (size_t)NR * DD * DD * sizeof(short);       // 128 KB
    const size_t epack_bytes  = (size_t)NE * sizeof(int);                   // 3.2 MB
    const size_t rowptr_bytes = (size_t)(NN + 1) * sizeof(int);
    const size_t cnt_bytes    = (size_t)NN * sizeof(int);
    const int    NB_SCAN      = (NN + 255) / 256;   // 196
    const size_t bsum_bytes   = (size_t)256 * sizeof(int);

    char* p = (char*)d_ws;
    float*          h_nb   = (float*)p;          p += hnb_bytes;
    unsigned short* hbf    = (unsigned short*)p; p += hbf_bytes;
    unsigned short* wbf    = (unsigned short*)p; p += wbf_bytes;
    unsigned short* wtbf   = (unsigned short*)p; p += wbf_bytes;
    int*            epack  = (int*)p;            p += epack_bytes;
    int*            rowptr = (int*)p;            p += rowptr_bytes;
    int*            cnt    = (int*)p;            p += cnt_bytes;
    int*            bsum   = (int*)p;            p += bsum_bytes;
    (void)ws_size;

    // ---- CSR build (shared by both layers) ----
    hipMemsetAsync(cnt, 0, cnt_bytes, stream);
    k_deg  <<<1024, 256, 0, stream>>>(dst, cnt);
    k_scan1<<<NB_SCAN, 256, 0, stream>>>(cnt, rowptr, bsum);
    k_scan2<<<1, 256, 0, stream>>>(bsum, NB_SCAN);
    k_scan3<<<NB_SCAN, 256, 0, stream>>>(rowptr, bsum, cnt);
    k_fill <<<1024, 256, 0, stream>>>(dst, src, rel_ids, cnt, epack);

    // ---- h0 ----
    k_copy_h0<<<(NN * DD + 255) / 256, 256, 0, stream>>>(node_ids, ent, out, hbf);

    for (int L = 0; L < 2; ++L) {
        int off_in = L * DD;
        int off_out = (L + 1) * DD;

        k_wprep <<<(NR * DD * DD + 255) / 256, 256, 0, stream>>>(W[L], wbf, wtbf);
        k_fused6<<<(NN + 15) / 16, 1024, 0, stream>>>(hbf, wbf, wtbf, relE,
                                                      rowptr, epack, h_nb);
        k_out2  <<<(NN + 63) / 64, 256, 0, stream>>>(h_nb, ra[L], rb[L], out,
                                                     off_in, off_out, hbf);
    }
}

// Round 12
// 434.829 us; speedup vs baseline: 1.2344x; 1.0550x over previous
//
#include <hip/hip_runtime.h>
#include <hip/hip_bf16.h>
#include <math.h>

#define NN 50000
#define NE 800000
#define NR 16
#define DD 64
#define OSTRIDE 192   // 3*D concat output stride
#define QSTRIDE 1032  // ushorts per node row in q_lds (1024 + 8 pad)

typedef __attribute__((ext_vector_type(8))) short bf16x8;
typedef __attribute__((ext_vector_type(4))) float f32x4;

__device__ inline float tanh_fast(float x) {
    return 1.f - 2.f / (__expf(2.f * x) + 1.f);
}
__device__ inline unsigned short f2bf(float f) {   // RNE f32 -> bf16
    unsigned u = __float_as_uint(f);
    return (unsigned short)((u + 0x7fffu + ((u >> 16) & 1u)) >> 16);
}
__device__ inline float bf2f(unsigned short s) {
    return __uint_as_float((unsigned)s << 16);
}

// ---------- CSR build ----------
__global__ void k_deg(const int* __restrict__ dst, int* __restrict__ cnt) {
    for (int e = blockIdx.x * blockDim.x + threadIdx.x; e < NE;
         e += gridDim.x * blockDim.x)
        atomicAdd(&cnt[dst[e]], 1);
}

// hierarchical exclusive scan over cnt[NN] -> rowptr, cursor
__global__ __launch_bounds__(256) void k_scan1(const int* __restrict__ cnt,
                                               int* __restrict__ rowptr,
                                               int* __restrict__ bsum) {
    __shared__ int sh[256];
    int b = blockIdx.x, t = threadIdx.x;
    int i = b * 256 + t;
    int v = (i < NN) ? cnt[i] : 0;
    sh[t] = v;
    __syncthreads();
    #pragma unroll
    for (int o = 1; o < 256; o <<= 1) {
        int u = (t >= o) ? sh[t - o] : 0;
        __syncthreads();
        sh[t] += u;
        __syncthreads();
    }
    if (i < NN) rowptr[i] = sh[t] - v;     // local exclusive
    if (t == 255) bsum[b] = sh[255];
}

__global__ __launch_bounds__(256) void k_scan2(int* __restrict__ bsum, int nb) {
    __shared__ int sh[256];
    int t = threadIdx.x;
    int v = (t < nb) ? bsum[t] : 0;
    sh[t] = v;
    __syncthreads();
    #pragma unroll
    for (int o = 1; o < 256; o <<= 1) {
        int u = (t >= o) ? sh[t - o] : 0;
        __syncthreads();
        sh[t] += u;
        __syncthreads();
    }
    if (t < nb) bsum[t] = sh[t] - v;       // exclusive block offsets
}

__global__ __launch_bounds__(256) void k_scan3(int* __restrict__ rowptr,
                                               const int* __restrict__ bsum,
                                               int* __restrict__ cursor) {
    int b = blockIdx.x, t = threadIdx.x;
    int i = b * 256 + t;
    if (i < NN) {
        int v = rowptr[i] + bsum[b];
        rowptr[i] = v;
        cursor[i] = v;
    }
    if (i == 0) rowptr[NN] = NE;
}

// epack[pos] = src | (rel<<16)
__global__ void k_fill(const int* __restrict__ dst, const int* __restrict__ src,
                       const int* __restrict__ rel, int* __restrict__ cursor,
                       int* __restrict__ epack) {
    for (int e = blockIdx.x * blockDim.x + threadIdx.x; e < NE;
         e += gridDim.x * blockDim.x) {
        int pos = atomicAdd(&cursor[dst[e]], 1);
        epack[pos] = src[e] | (rel[e] << 16);
    }
}

// ---------- h0 gather (f32 out slice + bf16 shadow) ----------
__global__ void k_copy_h0(const int* __restrict__ node_ids,
                          const float* __restrict__ ent,
                          float* __restrict__ out,
                          unsigned short* __restrict__ hbf) {
    int i = blockIdx.x * blockDim.x + threadIdx.x;
    if (i >= NN * DD) return;
    int n = i >> 6, d = i & 63;
    float v = ent[(size_t)node_ids[n] * DD + d];
    out[(size_t)n * OSTRIDE + d] = v;
    hbf[(size_t)n * DD + d] = f2bf(v);
}

// ---------- W -> bf16 tables: wbf[r][d][E], wtbf[r][E][d] ----------
__global__ void k_wprep(const float* __restrict__ W, unsigned short* __restrict__ wbf,
                        unsigned short* __restrict__ wtbf) {
    int i = blockIdx.x * blockDim.x + threadIdx.x;   // 16*64*64 = 65536
    if (i >= NR * DD * DD) return;
    int r = i >> 12, rem = i & 4095, d = rem >> 6, E = rem & 63;
    unsigned short v = f2bf(W[i]);
    wbf[i] = v;
    wtbf[(r << 12) | (E << 6) | d] = v;
}

// ---------- FUSED: q compute in LDS (MFMA) + edge softmax/aggregate ----------
// Block = 16 dst nodes, 1024 threads = 16 waves.
// Phase 1: wave w computes q[*, r=w] for the 16-node tile into q_lds (no HBM).
// Phase 2: wave w = node n0+w; 4x16-lane groups each process every 4th edge
// with 4 elems/lane, private online-softmax state, merged at the end.
__global__ __launch_bounds__(1024) void k_fused7(const unsigned short* __restrict__ hbf,
                                                 const unsigned short* __restrict__ wbf,
                                                 const unsigned short* __restrict__ wtbf,
                                                 const float* __restrict__ relE,
                                                 const int* __restrict__ rowptr,
                                                 const int* __restrict__ epack,
                                                 float* __restrict__ h_nb) {
    __shared__ __align__(16) unsigned short q_lds[16 * QSTRIDE];  // [ni][r*64+d], 33KB
    __shared__ __align__(16) unsigned short u_lds[16][16][72];    // per-wave slice, 37KB
    int n0 = blockIdx.x * 16;
    int t  = threadIdx.x;
    int w  = t >> 6, l = t & 63;          // wave = relation (phase1) = node (phase2)
    int l15 = l & 15, lg = l >> 4;
    int r = w;

    // ---- Phase 1: q[m, r, :] = W_r @ tanh(h[m,:]@W_r + e_r), m = 16-node tile ----
    {
        int ar = n0 + l15; if (ar >= NN) ar = NN - 1;
        const unsigned short* ap = hbf + (size_t)ar * DD + lg * 8;
        bf16x8 a0 = *(const bf16x8*)ap;
        bf16x8 a1 = *(const bf16x8*)(ap + 32);

        // GEMM1: T[m,E] = h[m,:] @ W_r  (B = wtbf rows = B^T)
        f32x4 acc[4];
        #pragma unroll
        for (int nt = 0; nt < 4; ++nt) acc[nt] = (f32x4){0.f, 0.f, 0.f, 0.f};
        const unsigned short* wtr = wtbf + (r << 12);
        #pragma unroll
        for (int nt = 0; nt < 4; ++nt) {
            const unsigned short* bp = wtr + (nt * 16 + l15) * DD + lg * 8;
            bf16x8 b0 = *(const bf16x8*)bp;
            bf16x8 b1 = *(const bf16x8*)(bp + 32);
            acc[nt] = __builtin_amdgcn_mfma_f32_16x16x32_bf16(a0, b0, acc[nt], 0, 0, 0);
            acc[nt] = __builtin_amdgcn_mfma_f32_16x16x32_bf16(a1, b1, acc[nt], 0, 0, 0);
        }

        // U = tanh(T + e_r) -> wave-private u_lds (per-wave DS ops are in-order)
        #pragma unroll
        for (int nt = 0; nt < 4; ++nt) {
            int E = nt * 16 + l15;
            float er = relE[r * DD + E];
            #pragma unroll
            for (int reg = 0; reg < 4; ++reg)
                u_lds[w][lg * 4 + reg][E] = f2bf(tanh_fast(acc[nt][reg] + er));
        }
        asm volatile("s_waitcnt lgkmcnt(0)" ::: "memory");

        // GEMM2: Q[m,d] = U[m,:] @ W_r^T  (B = wbf rows = B^T)
        const unsigned short* up = &u_lds[w][l15][lg * 8];
        bf16x8 u0 = *(const bf16x8*)up;
        bf16x8 u1 = *(const bf16x8*)(up + 32);

        f32x4 q4[4];
        #pragma unroll
        for (int nt = 0; nt < 4; ++nt) q4[nt] = (f32x4){0.f, 0.f, 0.f, 0.f};
        const unsigned short* wr = wbf + (r << 12);
        #pragma unroll
        for (int nt = 0; nt < 4; ++nt) {
            const unsigned short* bp = wr + (nt * 16 + l15) * DD + lg * 8;
            bf16x8 b0 = *(const bf16x8*)bp;
            bf16x8 b1 = *(const bf16x8*)(bp + 32);
            q4[nt] = __builtin_amdgcn_mfma_f32_16x16x32_bf16(u0, b0, q4[nt], 0, 0, 0);
            q4[nt] = __builtin_amdgcn_mfma_f32_16x16x32_bf16(u1, b1, q4[nt], 0, 0, 0);
        }

        // store to q_lds[m][r*64 + d]
        #pragma unroll
        for (int reg = 0; reg < 4; ++reg) {
            unsigned short* qp = q_lds + (lg * 4 + reg) * QSTRIDE + r * 64 + l15;
            #pragma unroll
            for (int nt = 0; nt < 4; ++nt)
                qp[nt * 16] = f2bf(q4[nt][reg]);
        }
    }
    __syncthreads();

    // ---- Phase 2: node n0+w; group g handles edges row0 + 4k + g ----
    int n = n0 + w;
    if (n >= NN) return;
    const unsigned short* ql = q_lds + w * QSTRIDE;
    int row0 = rowptr[n], row1 = rowptr[n + 1];
    int deg = row1 - row0;
    int g = lg;

    const float NEGBIG = -1e30f;
    float m = NEGBIG, zr = 0.f;
    float a0 = 0.f, a1 = 0.f, a2 = 0.f, a3 = 0.f;

    int steps = (deg + 3) >> 2;
    for (int k = 0; k < steps; ++k) {
        int idx = row0 + (k << 2) + g;
        bool ok = idx < row1;
        int p = epack[ok ? idx : row0];
        int s = p & 0xffff, rr = p >> 16;
        uint2 hu = *(const uint2*)(hbf + ((size_t)s << 6) + (l15 << 2));
        uint2 qu = *(const uint2*)(ql + rr * 64 + (l15 << 2));
        float h0 = __uint_as_float(hu.x << 16);
        float h1 = __uint_as_float(hu.x & 0xffff0000u);
        float h2 = __uint_as_float(hu.y << 16);
        float h3 = __uint_as_float(hu.y & 0xffff0000u);
        float q0 = __uint_as_float(qu.x << 16);
        float q1 = __uint_as_float(qu.x & 0xffff0000u);
        float q2 = __uint_as_float(qu.y << 16);
        float q3 = __uint_as_float(qu.y & 0xffff0000u);
        float d = h0 * q0 + h1 * q1 + h2 * q2 + h3 * q3;
        // 16-lane reduce (stays within the group)
        d += __shfl_xor(d, 1, 64);
        d += __shfl_xor(d, 2, 64);
        d += __shfl_xor(d, 4, 64);
        d += __shfl_xor(d, 8, 64);
        float v  = ok ? d : NEGBIG;
        float mn = fmaxf(m, v);
        float sc = __expf(m - mn);           // m==mn==NEGBIG -> exp(0)=1, state is 0
        float wg = ok ? __expf(v - mn) : 0.f;
        zr = zr * sc + wg;
        a0 = a0 * sc + wg * h0;
        a1 = a1 * sc + wg * h1;
        a2 = a2 * sc + wg * h2;
        a3 = a3 * sc + wg * h3;
        m = mn;
    }

    // merge the 4 group states (flash-attention style)
    float mo = fmaxf(m, __shfl_xor(m, 16, 64));
    float ms = fmaxf(mo, __shfl_xor(mo, 32, 64));
    float scg = __expf(m - ms);
    zr *= scg; a0 *= scg; a1 *= scg; a2 *= scg; a3 *= scg;
    zr += __shfl_xor(zr, 16, 64); zr += __shfl_xor(zr, 32, 64);
    a0 += __shfl_xor(a0, 16, 64); a0 += __shfl_xor(a0, 32, 64);
    a1 += __shfl_xor(a1, 16, 64); a1 += __shfl_xor(a1, 32, 64);
    a2 += __shfl_xor(a2, 16, 64); a2 += __shfl_xor(a2, 32, 64);
    a3 += __shfl_xor(a3, 16, 64); a3 += __shfl_xor(a3, 32, 64);

    if (g == 0) {
        float inv = (deg > 0) ? 1.f / zr : 0.f;
        float4 o = make_float4(a0 * inv, a1 * inv, a2 * inv, a3 * inv);
        *(float4*)&h_nb[((size_t)n << 6) + (l15 << 2)] = o;
    }
}

// ---------- epilogue GEMM (f32) + bf16 shadow of new h ----------
__global__ __launch_bounds__(256) void k_out2(const float* __restrict__ h_nb,
                                              const float* __restrict__ ra,
                                              const float* __restrict__ rb,
                                              float* __restrict__ out,
                                              int off_in, int off_out,
                                              unsigned short* __restrict__ hbf) {
    __shared__ __align__(16) float v1s[64][68];
    __shared__ __align__(16) float v2s[64][68];
    __shared__ __align__(16) float ws[2][64][64];
    int t = threadIdx.x;
    int n0 = blockIdx.x * 64;

    for (int i = t; i < 1024; i += 256) {
        int ni = i >> 4, c4 = (i & 15) * 4;
        int n = n0 + ni;
        float4 hv = make_float4(0.f, 0.f, 0.f, 0.f);
        float4 nb = make_float4(0.f, 0.f, 0.f, 0.f);
        if (n < NN) {
            hv = *(const float4*)&out[(size_t)n * OSTRIDE + off_in + c4];
            nb = *(const float4*)&h_nb[(size_t)n * DD + c4];
        }
        v1s[c4 + 0][ni] = hv.x + nb.x;  v2s[c4 + 0][ni] = hv.x * nb.x;
        v1s[c4 + 1][ni] = hv.y + nb.y;  v2s[c4 + 1][ni] = hv.y * nb.y;
        v1s[c4 + 2][ni] = hv.z + nb.z;  v2s[c4 + 2][ni] = hv.z * nb.z;
        v1s[c4 + 3][ni] = hv.w + nb.w;  v2s[c4 + 3][ni] = hv.w * nb.w;
    }
    for (int i = t; i < 2048; i += 256) {
        const float* base = (i < 1024) ? ra : rb;
        int rem = i & 1023;
        float4 v = *(const float4*)&base[rem * 4];
        int k = rem >> 4, c4 = (rem & 15) * 4;
        *(float4*)&ws[i >> 10][k][c4] = v;
    }
    __syncthreads();

    int nd0 = (t >> 4) * 4;
    int c0  = (t & 15) * 4;
    float a1[4][4] = {}, a2[4][4] = {};
    #pragma unroll 8
    for (int k = 0; k < 64; ++k) {
        float4 h1 = *(const float4*)&v1s[k][nd0];
        float4 h2 = *(const float4*)&v2s[k][nd0];
        float4 wa = *(const float4*)&ws[0][k][c0];
        float4 wb = *(const float4*)&ws[1][k][c0];
        float x1[4] = {h1.x, h1.y, h1.z, h1.w};
        float x2[4] = {h2.x, h2.y, h2.z, h2.w};
        #pragma unroll
        for (int i = 0; i < 4; ++i) {
            a1[i][0] += x1[i] * wa.x; a1[i][1] += x1[i] * wa.y;
            a1[i][2] += x1[i] * wa.z; a1[i][3] += x1[i] * wa.w;
            a2[i][0] += x2[i] * wb.x; a2[i][1] += x2[i] * wb.y;
            a2[i][2] += x2[i] * wb.z; a2[i][3] += x2[i] * wb.w;
        }
    }
    #pragma unroll
    for (int i = 0; i < 4; ++i) {
        int n = n0 + nd0 + i;
        if (n >= NN) continue;
        float4 o;
        float* po = (float*)&o;
        #pragma unroll
        for (int j = 0; j < 4; ++j) {
            float u1 = a1[i][j], u2 = a2[i][j];
            u1 = u1 > 0.f ? u1 : 0.01f * u1;
            u2 = u2 > 0.f ? u2 : 0.01f * u2;
            po[j] = u1 + u2;
        }
        *(float4*)&out[(size_t)n * OSTRIDE + off_out + c0] = o;
        hbf[(size_t)n * DD + c0 + 0] = f2bf(o.x);
        hbf[(size_t)n * DD + c0 + 1] = f2bf(o.y);
        hbf[(size_t)n * DD + c0 + 2] = f2bf(o.z);
        hbf[(size_t)n * DD + c0 + 3] = f2bf(o.w);
    }
}

// ---------- launch ----------
extern "C" void kernel_launch(void* const* d_in, const int* in_sizes, int n_in,
                              void* d_out, int out_size, void* d_ws, size_t ws_size,
                              hipStream_t stream) {
    const int*   node_ids = (const int*)d_in[0];
    const int*   rel_ids  = (const int*)d_in[1];
    const int*   src      = (const int*)d_in[2];
    const int*   dst      = (const int*)d_in[3];
    const float* ent      = (const float*)d_in[4];
    const float* relE     = (const float*)d_in[5];
    const float* W[2]  = {(const float*)d_in[6], (const float*)d_in[7]};
    const float* ra[2] = {(const float*)d_in[8], (const float*)d_in[10]};
    const float* rb[2] = {(const float*)d_in[9], (const float*)d_in[11]};
    float* out = (float*)d_out;

    const size_t hnb_bytes    = (size_t)NN * DD * sizeof(float);            // 12.8 MB
    const size_t hbf_bytes    = (size_t)NN * DD * sizeof(short);            // 6.4 MB
    const size_t wbf_bytes    = (size_t)NR * DD * DD * sizeof(short);       // 128 KB
    const size_t epack_bytes  = (size_t)NE * sizeof(int);                   // 3.2 MB
    const size_t rowptr_bytes = (size_t)(NN + 1) * sizeof(int);
    const size_t cnt_bytes    = (size_t)NN * sizeof(int);
    const int    NB_SCAN      = (NN + 255) / 256;   // 196
    const size_t bsum_bytes   = (size_t)256 * sizeof(int);

    char* p = (char*)d_ws;
    float*          h_nb   = (float*)p;          p += hnb_bytes;
    unsigned short* hbf    = (unsigned short*)p; p += hbf_bytes;
    unsigned short* wbf    = (unsigned short*)p; p += wbf_bytes;
    unsigned short* wtbf   = (unsigned short*)p; p += wbf_bytes;
    int*            epack  = (int*)p;            p += epack_bytes;
    int*            rowptr = (int*)p;            p += rowptr_bytes;
    int*            cnt    = (int*)p;            p += cnt_bytes;
    int*            bsum   = (int*)p;            p += bsum_bytes;
    (void)ws_size;

    // ---- CSR build (shared by both layers) ----
    hipMemsetAsync(cnt, 0, cnt_bytes, stream);
    k_deg  <<<1024, 256, 0, stream>>>(dst, cnt);
    k_scan1<<<NB_SCAN, 256, 0, stream>>>(cnt, rowptr, bsum);
    k_scan2<<<1, 256, 0, stream>>>(bsum, NB_SCAN);
    k_scan3<<<NB_SCAN, 256, 0, stream>>>(rowptr, bsum, cnt);
    k_fill <<<1024, 256, 0, stream>>>(dst, src, rel_ids, cnt, epack);

    // ---- h0 ----
    k_copy_h0<<<(NN * DD + 255) / 256, 256, 0, stream>>>(node_ids, ent, out, hbf);

    for (int L = 0; L < 2; ++L) {
        int off_in = L * DD;
        int off_out = (L + 1) * DD;

        k_wprep <<<(NR * DD * DD + 255) / 256, 256, 0, stream>>>(W[L], wbf, wtbf);
        k_fused7<<<(NN + 15) / 16, 1024, 0, stream>>>(hbf, wbf, wtbf, relE,
                                                      rowptr, epack, h_nb);
        k_out2  <<<(NN + 63) / 64, 256, 0, stream>>>(h_nb, ra[L], rb[L], out,
                                                     off_in, off_out, hbf);
    }
}

// Round 13
// 412.245 us; speedup vs baseline: 1.3020x; 1.0548x over previous
//
#include <hip/hip_runtime.h>
#include <hip/hip_bf16.h>
#include <math.h>

#define NN 50000
#define NE 800000
#define NR 16
#define DD 64
#define OSTRIDE 192   // 3*D concat output stride
#define QSTRIDE 1032  // f16 elems per node row in q_lds (1024 + 8 pad)

typedef _Float16 f16;
typedef f16 f16x8 __attribute__((ext_vector_type(8)));
typedef f16 f16x2 __attribute__((ext_vector_type(2)));
typedef __attribute__((ext_vector_type(4))) float f32x4;

__device__ inline float tanh_fast(float x) {
    return 1.f - 2.f / (__expf(2.f * x) + 1.f);
}

__device__ inline float dot2acc(f16x2 a, f16x2 b, float c) {
#if __has_builtin(__builtin_amdgcn_fdot2)
    return __builtin_amdgcn_fdot2(a, b, c, false);
#else
    return c + (float)a[0] * (float)b[0] + (float)a[1] * (float)b[1];
#endif
}

// ---------- CSR build ----------
__global__ void k_deg(const int* __restrict__ dst, int* __restrict__ cnt) {
    for (int e = blockIdx.x * blockDim.x + threadIdx.x; e < NE;
         e += gridDim.x * blockDim.x)
        atomicAdd(&cnt[dst[e]], 1);
}

__global__ __launch_bounds__(256) void k_scan1(const int* __restrict__ cnt,
                                               int* __restrict__ rowptr,
                                               int* __restrict__ bsum) {
    __shared__ int sh[256];
    int b = blockIdx.x, t = threadIdx.x;
    int i = b * 256 + t;
    int v = (i < NN) ? cnt[i] : 0;
    sh[t] = v;
    __syncthreads();
    #pragma unroll
    for (int o = 1; o < 256; o <<= 1) {
        int u = (t >= o) ? sh[t - o] : 0;
        __syncthreads();
        sh[t] += u;
        __syncthreads();
    }
    if (i < NN) rowptr[i] = sh[t] - v;
    if (t == 255) bsum[b] = sh[255];
}

__global__ __launch_bounds__(256) void k_scan2(int* __restrict__ bsum, int nb) {
    __shared__ int sh[256];
    int t = threadIdx.x;
    int v = (t < nb) ? bsum[t] : 0;
    sh[t] = v;
    __syncthreads();
    #pragma unroll
    for (int o = 1; o < 256; o <<= 1) {
        int u = (t >= o) ? sh[t - o] : 0;
        __syncthreads();
        sh[t] += u;
        __syncthreads();
    }
    if (t < nb) bsum[t] = sh[t] - v;
}

__global__ __launch_bounds__(256) void k_scan3(int* __restrict__ rowptr,
                                               const int* __restrict__ bsum,
                                               int* __restrict__ cursor) {
    int b = blockIdx.x, t = threadIdx.x;
    int i = b * 256 + t;
    if (i < NN) {
        int v = rowptr[i] + bsum[b];
        rowptr[i] = v;
        cursor[i] = v;
    }
    if (i == 0) rowptr[NN] = NE;
}

// epack[pos] = src | (rel<<16)
__global__ void k_fill(const int* __restrict__ dst, const int* __restrict__ src,
                       const int* __restrict__ rel, int* __restrict__ cursor,
                       int* __restrict__ epack) {
    for (int e = blockIdx.x * blockDim.x + threadIdx.x; e < NE;
         e += gridDim.x * blockDim.x) {
        int pos = atomicAdd(&cursor[dst[e]], 1);
        epack[pos] = src[e] | (rel[e] << 16);
    }
}

// ---------- h0 gather (f32 out slice + f16 shadow) ----------
__global__ void k_copy_h0(const int* __restrict__ node_ids,
                          const float* __restrict__ ent,
                          float* __restrict__ out,
                          f16* __restrict__ hf) {
    int i = blockIdx.x * blockDim.x + threadIdx.x;
    if (i >= NN * DD) return;
    int n = i >> 6, d = i & 63;
    float v = ent[(size_t)node_ids[n] * DD + d];
    out[(size_t)n * OSTRIDE + d] = v;
    hf[(size_t)n * DD + d] = (f16)v;
}

// ---------- W -> f16 tables: wf[r][d][E], wtf[r][E][d] ----------
__global__ void k_wprep(const float* __restrict__ W, f16* __restrict__ wf,
                        f16* __restrict__ wtf) {
    int i = blockIdx.x * blockDim.x + threadIdx.x;   // 16*64*64 = 65536
    if (i >= NR * DD * DD) return;
    int r = i >> 12, rem = i & 4095, d = rem >> 6, E = rem & 63;
    f16 v = (f16)W[i];
    wf[i] = v;
    wtf[(r << 12) | (E << 6) | d] = v;
}

// ---------- FUSED: q compute in LDS (f16 MFMA) + edge softmax/aggregate ----------
// Block = 16 dst nodes, 1024 threads = 16 waves.
// Phase 1: wave w computes q[*, r=w] for the tile into q_lds (no HBM).
// Phase 2: wave w = node n0+w; 8x8-lane groups, 8 edges in flight, fdot2 dots,
// no-max softmax (scores bounded, shift-invariant), f32 accumulation.
__global__ __launch_bounds__(1024) void k_fused8(const f16* __restrict__ hf,
                                                 const f16* __restrict__ wf,
                                                 const f16* __restrict__ wtf,
                                                 const float* __restrict__ relE,
                                                 const int* __restrict__ rowptr,
                                                 const int* __restrict__ epack,
                                                 float* __restrict__ h_nb) {
    __shared__ __align__(16) f16 q_lds[16 * QSTRIDE];   // [ni][r*64+d], 33KB
    __shared__ __align__(16) f16 u_lds[16][16][72];     // per-wave slice, 37KB
    int n0 = blockIdx.x * 16;
    int t  = threadIdx.x;
    int w  = t >> 6, l = t & 63;
    int l15 = l & 15, lg = l >> 4;
    int r = w;

    // ---- Phase 1: q[m, r, :] = W_r @ tanh(h[m,:]@W_r + e_r) ----
    {
        int ar = n0 + l15; if (ar >= NN) ar = NN - 1;
        const f16* ap = hf + (size_t)ar * DD + lg * 8;
        f16x8 a0 = *(const f16x8*)ap;
        f16x8 a1 = *(const f16x8*)(ap + 32);

        f32x4 acc[4];
        #pragma unroll
        for (int nt = 0; nt < 4; ++nt) acc[nt] = (f32x4){0.f, 0.f, 0.f, 0.f};
        const f16* wtr = wtf + (r << 12);
        #pragma unroll
        for (int nt = 0; nt < 4; ++nt) {
            const f16* bp = wtr + (nt * 16 + l15) * DD + lg * 8;
            f16x8 b0 = *(const f16x8*)bp;
            f16x8 b1 = *(const f16x8*)(bp + 32);
            acc[nt] = __builtin_amdgcn_mfma_f32_16x16x32_f16(a0, b0, acc[nt], 0, 0, 0);
            acc[nt] = __builtin_amdgcn_mfma_f32_16x16x32_f16(a1, b1, acc[nt], 0, 0, 0);
        }

        #pragma unroll
        for (int nt = 0; nt < 4; ++nt) {
            int E = nt * 16 + l15;
            float er = relE[r * DD + E];
            #pragma unroll
            for (int reg = 0; reg < 4; ++reg)
                u_lds[w][lg * 4 + reg][E] = (f16)tanh_fast(acc[nt][reg] + er);
        }
        asm volatile("s_waitcnt lgkmcnt(0)" ::: "memory");

        const f16* up = &u_lds[w][l15][lg * 8];
        f16x8 u0 = *(const f16x8*)up;
        f16x8 u1 = *(const f16x8*)(up + 32);

        f32x4 q4[4];
        #pragma unroll
        for (int nt = 0; nt < 4; ++nt) q4[nt] = (f32x4){0.f, 0.f, 0.f, 0.f};
        const f16* wr = wf + (r << 12);
        #pragma unroll
        for (int nt = 0; nt < 4; ++nt) {
            const f16* bp = wr + (nt * 16 + l15) * DD + lg * 8;
            f16x8 b0 = *(const f16x8*)bp;
            f16x8 b1 = *(const f16x8*)(bp + 32);
            q4[nt] = __builtin_amdgcn_mfma_f32_16x16x32_f16(u0, b0, q4[nt], 0, 0, 0);
            q4[nt] = __builtin_amdgcn_mfma_f32_16x16x32_f16(u1, b1, q4[nt], 0, 0, 0);
        }

        #pragma unroll
        for (int reg = 0; reg < 4; ++reg) {
            f16* qp = q_lds + (lg * 4 + reg) * QSTRIDE + r * 64 + l15;
            #pragma unroll
            for (int nt = 0; nt < 4; ++nt)
                qp[nt * 16] = (f16)q4[nt][reg];
        }
    }
    __syncthreads();

    // ---- Phase 2: node n0+w; group g (8 lanes) handles edges row0 + 8k + g ----
    int n = n0 + w;
    if (n >= NN) return;
    const f16* ql = q_lds + w * QSTRIDE;
    int row0 = rowptr[n], row1 = rowptr[n + 1];
    int deg = row1 - row0;
    int g  = l >> 3;       // group id 0..7
    int d8 = l & 7;        // element cluster: elems 8*d8 .. +7

    float zr = 0.f;
    float a[8] = {};

    int steps = (deg + 7) >> 3;
    for (int k = 0; k < steps; ++k) {
        int idx = row0 + (k << 3) + g;
        bool ok = idx < row1;
        int p = epack[ok ? idx : row0];
        int s = p & 0xffff, rr = p >> 16;
        f16x8 hv = *(const f16x8*)(hf + ((size_t)s << 6) + (d8 << 3));
        f16x8 qv = *(const f16x8*)(ql + (rr << 6) + (d8 << 3));
        float dp = 0.f;
        #pragma unroll
        for (int j = 0; j < 4; ++j) {
            f16x2 ha = {hv[2 * j], hv[2 * j + 1]};
            f16x2 qa = {qv[2 * j], qv[2 * j + 1]};
            dp = dot2acc(ha, qa, dp);
        }
        dp += __shfl_xor(dp, 1, 64);
        dp += __shfl_xor(dp, 2, 64);
        dp += __shfl_xor(dp, 4, 64);
        float wg = ok ? __expf(dp) : 0.f;   // no max shift: scores bounded, softmax shift-invariant
        zr += wg;
        #pragma unroll
        for (int j = 0; j < 8; ++j)
            a[j] = fmaf(wg, (float)hv[j], a[j]);   // v_fma_mix candidate
    }

    // merge the 8 group partial sums (pure sums, no max state)
    #pragma unroll
    for (int o = 8; o < 64; o <<= 1) {
        zr += __shfl_xor(zr, o, 64);
        #pragma unroll
        for (int j = 0; j < 8; ++j)
            a[j] += __shfl_xor(a[j], o, 64);
    }

    if (g == 0) {
        float inv = (deg > 0) ? 1.f / zr : 0.f;
        float4* dst4 = (float4*)&h_nb[((size_t)n << 6) + (d8 << 3)];
        dst4[0] = make_float4(a[0] * inv, a[1] * inv, a[2] * inv, a[3] * inv);
        dst4[1] = make_float4(a[4] * inv, a[5] * inv, a[6] * inv, a[7] * inv);
    }
}

// ---------- epilogue GEMM (f32) + f16 shadow of new h ----------
__global__ __launch_bounds__(256) void k_out2(const float* __restrict__ h_nb,
                                              const float* __restrict__ ra,
                                              const float* __restrict__ rb,
                                              float* __restrict__ out,
                                              int off_in, int off_out,
                                              f16* __restrict__ hf) {
    __shared__ __align__(16) float v1s[64][68];
    __shared__ __align__(16) float v2s[64][68];
    __shared__ __align__(16) float ws[2][64][64];
    int t = threadIdx.x;
    int n0 = blockIdx.x * 64;

    for (int i = t; i < 1024; i += 256) {
        int ni = i >> 4, c4 = (i & 15) * 4;
        int n = n0 + ni;
        float4 hv = make_float4(0.f, 0.f, 0.f, 0.f);
        float4 nb = make_float4(0.f, 0.f, 0.f, 0.f);
        if (n < NN) {
            hv = *(const float4*)&out[(size_t)n * OSTRIDE + off_in + c4];
            nb = *(const float4*)&h_nb[(size_t)n * DD + c4];
        }
        v1s[c4 + 0][ni] = hv.x + nb.x;  v2s[c4 + 0][ni] = hv.x * nb.x;
        v1s[c4 + 1][ni] = hv.y + nb.y;  v2s[c4 + 1][ni] = hv.y * nb.y;
        v1s[c4 + 2][ni] = hv.z + nb.z;  v2s[c4 + 2][ni] = hv.z * nb.z;
        v1s[c4 + 3][ni] = hv.w + nb.w;  v2s[c4 + 3][ni] = hv.w * nb.w;
    }
    for (int i = t; i < 2048; i += 256) {
        const float* base = (i < 1024) ? ra : rb;
        int rem = i & 1023;
        float4 v = *(const float4*)&base[rem * 4];
        int k = rem >> 4, c4 = (rem & 15) * 4;
        *(float4*)&ws[i >> 10][k][c4] = v;
    }
    __syncthreads();

    int nd0 = (t >> 4) * 4;
    int c0  = (t & 15) * 4;
    float a1[4][4] = {}, a2[4][4] = {};
    #pragma unroll 8
    for (int k = 0; k < 64; ++k) {
        float4 h1 = *(const float4*)&v1s[k][nd0];
        float4 h2 = *(const float4*)&v2s[k][nd0];
        float4 wa = *(const float4*)&ws[0][k][c0];
        float4 wb = *(const float4*)&ws[1][k][c0];
        float x1[4] = {h1.x, h1.y, h1.z, h1.w};
        float x2[4] = {h2.x, h2.y, h2.z, h2.w};
        #pragma unroll
        for (int i = 0; i < 4; ++i) {
            a1[i][0] += x1[i] * wa.x; a1[i][1] += x1[i] * wa.y;
            a1[i][2] += x1[i] * wa.z; a1[i][3] += x1[i] * wa.w;
            a2[i][0] += x2[i] * wb.x; a2[i][1] += x2[i] * wb.y;
            a2[i][2] += x2[i] * wb.z; a2[i][3] += x2[i] * wb.w;
        }
    }
    #pragma unroll
    for (int i = 0; i < 4; ++i) {
        int n = n0 + nd0 + i;
        if (n >= NN) continue;
        float4 o;
        float* po = (float*)&o;
        #pragma unroll
        for (int j = 0; j < 4; ++j) {
            float u1 = a1[i][j], u2 = a2[i][j];
            u1 = u1 > 0.f ? u1 : 0.01f * u1;
            u2 = u2 > 0.f ? u2 : 0.01f * u2;
            po[j] = u1 + u2;
        }
        *(float4*)&out[(size_t)n * OSTRIDE + off_out + c0] = o;
        hf[(size_t)n * DD + c0 + 0] = (f16)o.x;
        hf[(size_t)n * DD + c0 + 1] = (f16)o.y;
        hf[(size_t)n * DD + c0 + 2] = (f16)o.z;
        hf[(size_t)n * DD + c0 + 3] = (f16)o.w;
    }
}

// ---------- launch ----------
extern "C" void kernel_launch(void* const* d_in, const int* in_sizes, int n_in,
                              void* d_out, int out_size, void* d_ws, size_t ws_size,
                              hipStream_t stream) {
    const int*   node_ids = (const int*)d_in[0];
    const int*   rel_ids  = (const int*)d_in[1];
    const int*   src      = (const int*)d_in[2];
    const int*   dst      = (const int*)d_in[3];
    const float* ent      = (const float*)d_in[4];
    const float* relE     = (const float*)d_in[5];
    const float* W[2]  = {(const float*)d_in[6], (const float*)d_in[7]};
    const float* ra[2] = {(const float*)d_in[8], (const float*)d_in[10]};
    const float* rb[2] = {(const float*)d_in[9], (const float*)d_in[11]};
    float* out = (float*)d_out;

    const size_t hnb_bytes    = (size_t)NN * DD * sizeof(float);       // 12.8 MB
    const size_t hf_bytes     = (size_t)NN * DD * sizeof(f16);         // 6.4 MB
    const size_t wf_bytes     = (size_t)NR * DD * DD * sizeof(f16);    // 128 KB
    const size_t epack_bytes  = (size_t)NE * sizeof(int);              // 3.2 MB
    const size_t rowptr_bytes = (size_t)(NN + 1) * sizeof(int);
    const size_t cnt_bytes    = (size_t)NN * sizeof(int);
    const int    NB_SCAN      = (NN + 255) / 256;   // 196
    const size_t bsum_bytes   = (size_t)256 * sizeof(int);

    char* p = (char*)d_ws;
    float* h_nb   = (float*)p; p += hnb_bytes;
    f16*   hf     = (f16*)p;   p += hf_bytes;
    f16*   wf     = (f16*)p;   p += wf_bytes;
    f16*   wtf    = (f16*)p;   p += wf_bytes;
    int*   epack  = (int*)p;   p += epack_bytes;
    int*   rowptr = (int*)p;   p += rowptr_bytes;
    int*   cnt    = (int*)p;   p += cnt_bytes;
    int*   bsum   = (int*)p;   p += bsum_bytes;
    (void)ws_size;

    // ---- CSR build (shared by both layers) ----
    hipMemsetAsync(cnt, 0, cnt_bytes, stream);
    k_deg  <<<1024, 256, 0, stream>>>(dst, cnt);
    k_scan1<<<NB_SCAN, 256, 0, stream>>>(cnt, rowptr, bsum);
    k_scan2<<<1, 256, 0, stream>>>(bsum, NB_SCAN);
    k_scan3<<<NB_SCAN, 256, 0, stream>>>(rowptr, bsum, cnt);
    k_fill <<<1024, 256, 0, stream>>>(dst, src, rel_ids, cnt, epack);

    // ---- h0 ----
    k_copy_h0<<<(NN * DD + 255) / 256, 256, 0, stream>>>(node_ids, ent, out, hf);

    for (int L = 0; L < 2; ++L) {
        int off_in = L * DD;
        int off_out = (L + 1) * DD;

        k_wprep <<<(NR * DD * DD + 255) / 256, 256, 0, stream>>>(W[L], wf, wtf);
        k_fused8<<<(NN + 15) / 16, 1024, 0, stream>>>(hf, wf, wtf, relE,
                                                      rowptr, epack, h_nb);
        k_out2  <<<(NN + 63) / 64, 256, 0, stream>>>(h_nb, ra[L], rb[L], out,
                                                     off_in, off_out, hf);
    }
}